// Round 1
// baseline (130.365 us; speedup 1.0000x reference)
//
#include <hip/hip_runtime.h>
#include <math.h>

#define NBATCH 16
#define NANCH  3
#define NHH    64
#define NWW    64
#define NTT    50
#define NCLS   80
#define HW     (NHH*NWW)          // 4096
#define CELLS  (NBATCH*NANCH*HW)  // 196608

// anchors / stride
#define AW0 1.875f
#define AW1 3.875f
#define AW2 3.6875f
#define AH0 3.8125f
#define AH1 2.8125f
#define AH2 7.4375f

__global__ __launch_bounds__(256) void yolo_loss_kernel(
    const float* __restrict__ out,     // (16, 255, 64, 64)
    const float* __restrict__ target,  // (16, 250)
    float* __restrict__ loss)          // scalar, pre-zeroed
{
    __shared__ float s_gx[NTT], s_gy[NTT], s_gw[NTT], s_gh[NTT];
    __shared__ int   s_meta[NTT];   // valid<<15 | best<<12 | gj<<6 | gi
    __shared__ float s_part[4];

    const int tid = threadIdx.x;
    const int b   = blockIdx.x / 48;          // 48 blocks per batch image

    // ---- per-block GT prep (50 boxes) ----
    if (tid < NTT) {
        const float* tb0 = target + b * (NTT * 5);
        const float* tb  = tb0 + tid * 5;
        // valid = cumprod(cx != 0) up to and including t
        bool valid = true;
        for (int tt = 0; tt <= tid; ++tt)
            if (tb0[tt * 5 + 1] == 0.0f) { valid = false; break; }

        float gx = tb[1] * NWW, gy = tb[2] * NHH;
        float gw = tb[3] * NWW, gh = tb[4] * NHH;

        // best anchor: IoU of (0,0,gw,gh) vs (0,0,aw,ah); first max wins
        float ga = gw * gh;
        float i0 = fminf(gw, AW0) * fminf(gh, AH0);
        float i1 = fminf(gw, AW1) * fminf(gh, AH1);
        float i2 = fminf(gw, AW2) * fminf(gh, AH2);
        float r0 = i0 / (ga + AW0 * AH0 - i0);
        float r1 = i1 / (ga + AW1 * AH1 - i1);
        float r2 = i2 / (ga + AW2 * AH2 - i2);
        int best = 0; float bv = r0;
        if (r1 > bv) { bv = r1; best = 1; }
        if (r2 > bv) { bv = r2; best = 2; }

        int gi = (int)floorf(gx); gi = gi < 0 ? 0 : (gi > NWW - 1 ? NWW - 1 : gi);
        int gj = (int)floorf(gy); gj = gj < 0 ? 0 : (gj > NHH - 1 ? NHH - 1 : gj);

        s_gx[tid] = gx; s_gy[tid] = gy; s_gw[tid] = gw; s_gh[tid] = gh;
        s_meta[tid] = valid ? ((1 << 15) | (best << 12) | (gj << 6) | gi) : 0;
    }
    __syncthreads();

    // ---- per-cell work ----
    const int cell = blockIdx.x * 256 + tid;
    const int rem  = cell % (NANCH * HW);
    const int a    = rem / HW;
    const int hw   = rem % HW;
    const int h    = hw >> 6;
    const int w    = hw & 63;

    const float* base = out + ((size_t)b * (NANCH * (5 + NCLS)) + (size_t)a * (5 + NCLS)) * HW + hw;
    const float r0 = base[0];
    const float r1 = base[HW];
    const float r2 = base[2 * HW];
    const float r3 = base[3 * HW];
    const float r4 = base[4 * HW];

    const float sx = 1.0f / (1.0f + expf(-r0));
    const float sy = 1.0f / (1.0f + expf(-r1));

    // reference's anchor-broadcast quirk: effective anchor = (3b+a)//16
    const int aidx = (3 * b + a) >> 4;
    const float aw = aidx == 0 ? AW0 : (aidx == 1 ? AW1 : AW2);
    const float ah = aidx == 0 ? AH0 : (aidx == 1 ? AH1 : AH2);

    const float px = sx + (float)w;
    const float py = sy + (float)h;
    const float pw = expf(r2) * aw;
    const float ph = expf(r3) * ah;

    const float hx0 = px - pw * 0.5f, hx1 = px + pw * 0.5f;
    const float hy0 = py - ph * 0.5f, hy1 = py + ph * 0.5f;

    float curmax = 0.0f;
    int   tlast  = -1;
    #pragma unroll 1
    for (int t = 0; t < NTT; ++t) {
        const int m = s_meta[t];
        if (m != 0) {
            const float gx = s_gx[t], gy = s_gy[t];
            const float gw = s_gw[t], gh = s_gh[t];
            const float mx = fminf(hx0, gx - gw * 0.5f);
            const float Mx = fmaxf(hx1, gx + gw * 0.5f);
            const float my = fminf(hy0, gy - gh * 0.5f);
            const float My = fmaxf(hy1, gy + gh * 0.5f);
            const float cw = pw + gw - (Mx - mx);
            const float ch = ph + gh - (My - my);
            const float carea = (cw <= 0.0f || ch <= 0.0f) ? 0.0f : cw * ch;
            const float uarea = pw * ph + gw * gh - carea;
            curmax = fmaxf(curmax, carea / uarea);
            if ((((m >> 12) & 3) == a) && (((m >> 6) & 63) == h) && ((m & 63) == w))
                tlast = t;  // sequential scan: last valid t wins
        }
    }

    const float conf = 1.0f / (1.0f + expf(-r4));
    float lsum;
    if (tlast >= 0) {
        const int m    = s_meta[tlast];
        const int best = (m >> 12) & 3;
        const float baw = best == 0 ? AW0 : (best == 1 ? AW1 : AW2);
        const float bah = best == 0 ? AH0 : (best == 1 ? AH1 : AH2);
        const float tx = s_gx[tlast] - (float)(m & 63);
        const float ty = s_gy[tlast] - (float)((m >> 6) & 63);
        const float tw = logf(s_gw[tlast] / baw);
        const float th = logf(s_gh[tlast] / bah);
        const int   tc = (int)target[b * (NTT * 5) + tlast * 5];

        const float dx = sx - tx, dy = sy - ty, dw = r2 - tw, dh = r3 - th;
        const float dc = conf - 1.0f;
        lsum = dc * dc + 0.5f * (dx * dx + dy * dy + dw * dw + dh * dh);

        // class NLL: -log_softmax(logits)[tc]
        const float* cb = base + 5 * HW;
        float mv = -INFINITY;
        for (int k = 0; k < NCLS; ++k) mv = fmaxf(mv, cb[k * HW]);
        float se = 0.0f;
        for (int k = 0; k < NCLS; ++k) se += expf(cb[k * HW] - mv);
        lsum += -(cb[tc * HW] - mv - logf(se));
    } else {
        lsum = (curmax > 0.5f) ? 0.0f : conf * conf;
    }

    // ---- reduce: wave shuffle -> LDS -> one atomic per block ----
    float v = lsum;
    #pragma unroll
    for (int off = 32; off > 0; off >>= 1) v += __shfl_down(v, off, 64);
    const int lane = tid & 63, wid = tid >> 6;
    if (lane == 0) s_part[wid] = v;
    __syncthreads();
    if (tid == 0)
        atomicAdd(loss, s_part[0] + s_part[1] + s_part[2] + s_part[3]);
}

extern "C" void kernel_launch(void* const* d_in, const int* in_sizes, int n_in,
                              void* d_out, int out_size, void* d_ws, size_t ws_size,
                              hipStream_t stream) {
    const float* out_t  = (const float*)d_in[0];   // (16, 255, 64, 64) f32
    const float* target = (const float*)d_in[1];   // (16, 250) f32
    float* loss = (float*)d_out;

    hipMemsetAsync(loss, 0, sizeof(float), stream);
    yolo_loss_kernel<<<CELLS / 256, 256, 0, stream>>>(out_t, target, loss);
}